// Round 13
// baseline (299.674 us; speedup 1.0000x reference)
//
#include <hip/hip_runtime.h>
#include <hip/hip_bf16.h>

// ---------------------------------------------------------------------------
// EncoderGNN: 3-layer GINE encoder, N=50000, E=800000, H=128.
// Round 13: (a) mlp_mfma split across 2 waves per 16-row tile (each wave does
// half the output channels of both GEMMs; t shared via LDS) -> 6250 waves
// (24/CU) vs 3125 (12/CU), half the weight traffic per wave. (b) agg edge
// loop unrolled x16 -> one 16-deep gather batch covers an average node in a
// single latency wait. CSR counting sort (r11) + r6 agg form unchanged.
// ---------------------------------------------------------------------------

#define HDIM 128
#define NCH 1024          // histogram chunks
#define NPB 256           // nodes per bucket

typedef unsigned int uint32;
typedef unsigned short ushort16;
typedef __attribute__((ext_vector_type(8))) short short8;
typedef __attribute__((ext_vector_type(4))) float f32x4;
typedef __attribute__((ext_vector_type(2))) float f32x2;

__device__ __forceinline__ ushort16 f2bf(float f) {
    uint32 u = __float_as_uint(f);
    u += 0x7fff + ((u >> 16) & 1);      // round-to-nearest-even
    return (ushort16)(u >> 16);
}
__device__ __forceinline__ float bflo(uint32 g) { return __uint_as_float(g << 16); }
__device__ __forceinline__ float bfhi(uint32 g) { return __uint_as_float(g & 0xffff0000u); }

// ---------------- CSR build: counting sort ----------------
__global__ __launch_bounds__(256) void hist_kernel(const int* __restrict__ dstIdx,
                                                   int* __restrict__ histM, int E, int NB) {
    __shared__ int hist[256];
    const int b = blockIdx.x;
    for (int j = threadIdx.x; j < NB; j += 256) hist[j] = 0;
    __syncthreads();
    const int epb = (E + NCH - 1) / NCH;
    const int e0 = b * epb, e1 = min(e0 + epb, E);
    for (int e = e0 + threadIdx.x; e < e1; e += 256)
        atomicAdd(&hist[dstIdx[e] >> 8], 1);
    __syncthreads();
    for (int j = threadIdx.x; j < NB; j += 256)
        histM[j * NCH + b] = hist[j];
}

__global__ __launch_bounds__(256) void partial_kernel(const int* __restrict__ F,
                                                      int* __restrict__ partials, int M) {
    __shared__ int red[256];
    int i = blockIdx.x * 256 + threadIdx.x;
    red[threadIdx.x] = (i < M) ? F[i] : 0;
    __syncthreads();
#pragma unroll
    for (int off = 128; off > 0; off >>= 1) {
        if (threadIdx.x < off) red[threadIdx.x] += red[threadIdx.x + off];
        __syncthreads();
    }
    if (threadIdx.x == 0) partials[blockIdx.x] = red[0];
}

__global__ __launch_bounds__(1024) void scan_partials_kernel(const int* __restrict__ partials,
                                                             int* __restrict__ offsets, int nb) {
    __shared__ int buf[1024];
    int tid = threadIdx.x;
    int v0 = (tid < nb) ? partials[tid] : 0;
    buf[tid] = v0;
    __syncthreads();
#pragma unroll
    for (int off = 1; off < 1024; off <<= 1) {
        int v = (tid >= off) ? buf[tid - off] : 0;
        __syncthreads();
        buf[tid] += v;
        __syncthreads();
    }
    if (tid < nb) offsets[tid] = buf[tid] - v0;   // exclusive
}

__global__ __launch_bounds__(256) void excl_out_kernel(const int* __restrict__ F,
                                                       const int* __restrict__ offsets,
                                                       int* __restrict__ Fscan, int M) {
    __shared__ int buf[256];
    int tid = threadIdx.x;
    int i = blockIdx.x * 256 + tid;
    int v = (i < M) ? F[i] : 0;
    buf[tid] = v;
    __syncthreads();
#pragma unroll
    for (int off = 1; off < 256; off <<= 1) {
        int t = (tid >= off) ? buf[tid - off] : 0;
        __syncthreads();
        buf[tid] += t;
        __syncthreads();
    }
    if (i < M) Fscan[i] = buf[tid] - v + offsets[blockIdx.x];
}

__global__ __launch_bounds__(256) void chunk_scatter_kernel(
        const int* __restrict__ srcIdx, const int* __restrict__ dstIdx,
        const float* __restrict__ edge_attr, const int* __restrict__ Fscan,
        int4* __restrict__ tmp, int E, int NB) {
    __shared__ int cur[256];
    const int b = blockIdx.x;
    for (int j = threadIdx.x; j < NB; j += 256) cur[j] = Fscan[j * NCH + b];
    __syncthreads();
    const int epb = (E + NCH - 1) / NCH;
    const int e0 = b * epb, e1 = min(e0 + epb, E);
    for (int e = e0 + threadIdx.x; e < e1; e += 256) {
        int d = dstIdx[e];
        int r = atomicAdd(&cur[d >> 8], 1);
        float4 ea = *(const float4*)(edge_attr + (size_t)e * 4);
        int4 rec;
        rec.x = srcIdx[e];
        rec.y = (int)(((uint32)f2bf(ea.y) << 16) | (uint32)f2bf(ea.x));
        rec.z = (int)(((uint32)f2bf(ea.w) << 16) | (uint32)f2bf(ea.z));
        rec.w = d;
        tmp[r] = rec;
    }
}

__global__ __launch_bounds__(256) void bucket_sort_kernel(
        const int4* __restrict__ tmp, const int* __restrict__ Fscan,
        int* __restrict__ row_ptr, int4* __restrict__ adj, int E, int NB, int N) {
    __shared__ int cnt[256];
    __shared__ int cur[256];
    const int bkt = blockIdx.x;
    const int tid = threadIdx.x;
    const int base = Fscan[bkt * NCH];
    const int endb = (bkt + 1 < NB) ? Fscan[(bkt + 1) * NCH] : E;

    cnt[tid] = 0;
    __syncthreads();
    for (int i = base + tid; i < endb; i += 256)
        atomicAdd(&cnt[tmp[i].w & 255], 1);
    __syncthreads();
    int orig = cnt[tid];
#pragma unroll
    for (int off = 1; off < 256; off <<= 1) {
        int v = (tid >= off) ? cnt[tid - off] : 0;
        __syncthreads();
        cnt[tid] += v;
        __syncthreads();
    }
    int excl = cnt[tid] - orig;
    int node = bkt * NPB + tid;
    if (node <= N) row_ptr[node] = base + excl;
    cur[tid] = base + excl;
    __syncthreads();
    for (int i = base + tid; i < endb; i += 256) {
        int4 rec = tmp[i];
        int pos = atomicAdd(&cur[rec.w & 255], 1);
        adj[pos] = rec;
    }
}

// ---------------- weight prep: bf16 + transpose (once per call) ----------------
__global__ void prep_weights(const float* __restrict__ W1, const float* __restrict__ W2,
                             ushort16* __restrict__ Wb1t, ushort16* __restrict__ Wb2t, int total) {
    int idx = blockIdx.x * 256 + threadIdx.x;
    if (idx >= total) return;
    int l = idx >> 14;
    int rem = idx & 16383;
    int n = rem >> 7, k = rem & 127;
    size_t src = (size_t)l * 16384 + (size_t)k * 128 + n;
    size_t dst = (size_t)l * 16384 + (size_t)n * 128 + k;
    Wb1t[dst] = f2bf(W1[src]);
    Wb2t[dst] = f2bf(W2[src]);
}

// ---------------- node embedding (writes bf16 h) ----------------
__global__ void embed_kernel(const int* __restrict__ x_type, const float* __restrict__ x_feat,
                             const float* __restrict__ type_embed, const float* __restrict__ featW,
                             const float* __restrict__ featb, ushort16* __restrict__ h, int N) {
    int idx = blockIdx.x * 256 + threadIdx.x;
    int n = idx >> 7, c = idx & 127;
    if (n >= N) return;
    int t = x_type[n];
    float acc = type_embed[(size_t)t * HDIM + c] + featb[c];
#pragma unroll
    for (int k = 0; k < 7; ++k)
        acc = fmaf(x_feat[(size_t)n * 7 + k], featW[(size_t)k * HDIM + c], acc);
    h[(size_t)n * HDIM + c] = f2bf(acc);
}

// ---------------- aggregation: r6 form, unroll x16 ----------------
__global__ __launch_bounds__(128) void agg_kernel(
        const uint32* __restrict__ hq,       // [N][64] packed bf16x2
        const int* __restrict__ row_ptr,
        const int4* __restrict__ adj,        // 16B records (uniform per wave)
        const float* __restrict__ edgeW, const float* __restrict__ edgeb,
        const float* __restrict__ eps, int l, uint32* __restrict__ zq, int N) {
    const int node = blockIdx.x * 2 + (threadIdx.x >> 6);
    const int lane = threadIdx.x & 63;
    if (node >= N) return;
    const int c0 = 2 * lane;
    const f32x2 w0 = {edgeW[c0],       edgeW[c0 + 1]};
    const f32x2 w1 = {edgeW[128 + c0], edgeW[128 + c0 + 1]};
    const f32x2 w2 = {edgeW[256 + c0], edgeW[256 + c0 + 1]};
    const f32x2 w3 = {edgeW[384 + c0], edgeW[384 + c0 + 1]};
    const f32x2 eb = {edgeb[c0],       edgeb[c0 + 1]};

    const int beg = __builtin_amdgcn_readfirstlane(row_ptr[node]);
    const int end = __builtin_amdgcn_readfirstlane(row_ptr[node + 1]);

    const uint32 gs = hq[(size_t)node * 64 + lane];   // self-term early

    f32x2 accA = {0.f, 0.f}, accB = {0.f, 0.f};

#define EDGE(Q, G, ACC) {                                                     \
        f32x2 e = eb;                                                         \
        e += bflo((uint32)(Q).y) * w0;                                        \
        e += bfhi((uint32)(Q).y) * w1;                                        \
        e += bflo((uint32)(Q).z) * w2;                                        \
        e += bfhi((uint32)(Q).z) * w3;                                        \
        ACC.x += fmaxf(bflo(G) + e.x, 0.f);                                   \
        ACC.y += fmaxf(bfhi(G) + e.y, 0.f);                                   \
    }

    int i = beg;
    for (; i + 16 <= end; i += 16) {
        int4 q0 = adj[i + 0],  q1 = adj[i + 1],  q2 = adj[i + 2],  q3 = adj[i + 3];
        int4 q4 = adj[i + 4],  q5 = adj[i + 5],  q6 = adj[i + 6],  q7 = adj[i + 7];
        int4 q8 = adj[i + 8],  q9 = adj[i + 9],  qa = adj[i + 10], qb = adj[i + 11];
        int4 qc = adj[i + 12], qd = adj[i + 13], qe = adj[i + 14], qf = adj[i + 15];
        uint32 g0 = hq[(size_t)q0.x * 64 + lane];
        uint32 g1 = hq[(size_t)q1.x * 64 + lane];
        uint32 g2 = hq[(size_t)q2.x * 64 + lane];
        uint32 g3 = hq[(size_t)q3.x * 64 + lane];
        uint32 g4 = hq[(size_t)q4.x * 64 + lane];
        uint32 g5 = hq[(size_t)q5.x * 64 + lane];
        uint32 g6 = hq[(size_t)q6.x * 64 + lane];
        uint32 g7 = hq[(size_t)q7.x * 64 + lane];
        uint32 g8 = hq[(size_t)q8.x * 64 + lane];
        uint32 g9 = hq[(size_t)q9.x * 64 + lane];
        uint32 ga = hq[(size_t)qa.x * 64 + lane];
        uint32 gb = hq[(size_t)qb.x * 64 + lane];
        uint32 gc = hq[(size_t)qc.x * 64 + lane];
        uint32 gd = hq[(size_t)qd.x * 64 + lane];
        uint32 ge = hq[(size_t)qe.x * 64 + lane];
        uint32 gf = hq[(size_t)qf.x * 64 + lane];
        EDGE(q0, g0, accA); EDGE(q1, g1, accB);
        EDGE(q2, g2, accA); EDGE(q3, g3, accB);
        EDGE(q4, g4, accA); EDGE(q5, g5, accB);
        EDGE(q6, g6, accA); EDGE(q7, g7, accB);
        EDGE(q8, g8, accA); EDGE(q9, g9, accB);
        EDGE(qa, ga, accA); EDGE(qb, gb, accB);
        EDGE(qc, gc, accA); EDGE(qd, gd, accB);
        EDGE(qe, ge, accA); EDGE(qf, gf, accB);
    }
    for (; i + 8 <= end; i += 8) {
        int4 q0 = adj[i + 0], q1 = adj[i + 1], q2 = adj[i + 2], q3 = adj[i + 3];
        int4 q4 = adj[i + 4], q5 = adj[i + 5], q6 = adj[i + 6], q7 = adj[i + 7];
        uint32 g0 = hq[(size_t)q0.x * 64 + lane];
        uint32 g1 = hq[(size_t)q1.x * 64 + lane];
        uint32 g2 = hq[(size_t)q2.x * 64 + lane];
        uint32 g3 = hq[(size_t)q3.x * 64 + lane];
        uint32 g4 = hq[(size_t)q4.x * 64 + lane];
        uint32 g5 = hq[(size_t)q5.x * 64 + lane];
        uint32 g6 = hq[(size_t)q6.x * 64 + lane];
        uint32 g7 = hq[(size_t)q7.x * 64 + lane];
        EDGE(q0, g0, accA); EDGE(q1, g1, accB);
        EDGE(q2, g2, accA); EDGE(q3, g3, accB);
        EDGE(q4, g4, accA); EDGE(q5, g5, accB);
        EDGE(q6, g6, accA); EDGE(q7, g7, accB);
    }
    for (; i + 4 <= end; i += 4) {
        int4 q0 = adj[i + 0], q1 = adj[i + 1], q2 = adj[i + 2], q3 = adj[i + 3];
        uint32 g0 = hq[(size_t)q0.x * 64 + lane];
        uint32 g1 = hq[(size_t)q1.x * 64 + lane];
        uint32 g2 = hq[(size_t)q2.x * 64 + lane];
        uint32 g3 = hq[(size_t)q3.x * 64 + lane];
        EDGE(q0, g0, accA); EDGE(q1, g1, accB);
        EDGE(q2, g2, accA); EDGE(q3, g3, accB);
    }
    for (; i < end; ++i) {
        int4 q = adj[i];
        uint32 g = hq[(size_t)q.x * 64 + lane];
        EDGE(q, g, accA);
    }
#undef EDGE

    const float ep = 1.0f + eps[l];
    float zl = fmaf(ep, bflo(gs), accA.x + accB.x);
    float zh = fmaf(ep, bfhi(gs), accA.y + accB.y);
    zq[(size_t)node * 64 + lane] = ((uint32)f2bf(zh) << 16) | (uint32)f2bf(zl);
}

// ---------------- MFMA MLP: 2 waves per 16-row tile, N-dim split ----------------
// Wave w computes output channels [w*64, w*64+64) of BOTH GEMMs; the full t
// tile is shared through LDS. Per-wave: 16+16 MFMA, half the weight traffic.
#define T_STRIDE 136   // shorts; 272B rows: 16B-aligned for b128 reads
__global__ __launch_bounds__(128) void mlp_mfma(
        const ushort16* __restrict__ zq,     // [N64][128] bf16
        const ushort16* __restrict__ Wb1t,   // [128 n][128 k] bf16
        const float* __restrict__ b1,
        const ushort16* __restrict__ Wb2t,
        const float* __restrict__ b2,
        ushort16* __restrict__ h_out, int N) {
    __shared__ ushort16 t_lds[16 * T_STRIDE];
    const int w = threadIdx.x >> 6;
    const int lane = threadIdx.x & 63;
    const int c = lane & 15, g = lane >> 4;
    const int row0 = blockIdx.x * 16;

    // ---- GEMM1: t^T[w*64 .. w*64+64) = W1^T @ z^T ----
    const ushort16* zrow = zq + (size_t)(row0 + c) * HDIM + g * 8;
    short8 bf[4];
#pragma unroll
    for (int kk = 0; kk < 4; ++kk)
        bf[kk] = *(const short8*)(zrow + kk * 32);

    f32x4 acc[4];
#pragma unroll
    for (int nn = 0; nn < 4; ++nn) {
        int n = w * 4 + nn;
        float4 bb = *(const float4*)(b1 + n * 16 + g * 4);
        acc[nn] = (f32x4){bb.x, bb.y, bb.z, bb.w};
    }
#pragma unroll
    for (int kk = 0; kk < 4; ++kk) {
#pragma unroll
        for (int nn = 0; nn < 4; ++nn) {
            int n = w * 4 + nn;
            short8 af = *(const short8*)(Wb1t + (size_t)(n * 16 + c) * HDIM + kk * 32 + g * 8);
            acc[nn] = __builtin_amdgcn_mfma_f32_16x16x32_bf16(af, bf[kk], acc[nn], 0, 0, 0);
        }
    }
#pragma unroll
    for (int nn = 0; nn < 4; ++nn) {
        int n = w * 4 + nn;
        ushort4 u;
        u.x = f2bf(fmaxf(acc[nn][0], 0.f));
        u.y = f2bf(fmaxf(acc[nn][1], 0.f));
        u.z = f2bf(fmaxf(acc[nn][2], 0.f));
        u.w = f2bf(fmaxf(acc[nn][3], 0.f));
        *(ushort4*)(&t_lds[c * T_STRIDE + n * 16 + g * 4]) = u;
    }
    __syncthreads();

    // ---- GEMM2: h^T[w*64 .. w*64+64) = W2^T @ t^T (full-K t from LDS) ----
    short8 bf2[4];
#pragma unroll
    for (int kk = 0; kk < 4; ++kk)
        bf2[kk] = *(const short8*)(&t_lds[c * T_STRIDE + kk * 32 + g * 8]);

    f32x4 acc2[4];
#pragma unroll
    for (int nn = 0; nn < 4; ++nn) {
        int n = w * 4 + nn;
        float4 bb = *(const float4*)(b2 + n * 16 + g * 4);
        acc2[nn] = (f32x4){bb.x, bb.y, bb.z, bb.w};
    }
#pragma unroll
    for (int kk = 0; kk < 4; ++kk) {
#pragma unroll
        for (int nn = 0; nn < 4; ++nn) {
            int n = w * 4 + nn;
            short8 af = *(const short8*)(Wb2t + (size_t)(n * 16 + c) * HDIM + kk * 32 + g * 8);
            acc2[nn] = __builtin_amdgcn_mfma_f32_16x16x32_bf16(af, bf2[kk], acc2[nn], 0, 0, 0);
        }
    }
    if (row0 + c < N) {
#pragma unroll
        for (int nn = 0; nn < 4; ++nn) {
            int n = w * 4 + nn;
            ushort4 u;
            u.x = f2bf(fmaxf(acc2[nn][0], 0.f));
            u.y = f2bf(fmaxf(acc2[nn][1], 0.f));
            u.z = f2bf(fmaxf(acc2[nn][2], 0.f));
            u.w = f2bf(fmaxf(acc2[nn][3], 0.f));
            *(ushort4*)(h_out + (size_t)(row0 + c) * HDIM + n * 16 + g * 4) = u;
        }
    }
}

// ---------------- output projection (reads bf16 h) ----------------
__global__ void out_kernel(const uint32* __restrict__ hq, const float* __restrict__ Wout,
                           const float* __restrict__ bout, float* __restrict__ out, int N) {
    int idx = blockIdx.x * 256 + threadIdx.x;
    int n = idx >> 4, pe = idx & 15;
    if (n >= N) return;
    float acc = bout[pe];
#pragma unroll 8
    for (int k2 = 0; k2 < 64; ++k2) {
        uint32 g = hq[(size_t)n * 64 + k2];
        acc = fmaf(bflo(g), Wout[(2 * k2) * 16 + pe], acc);
        acc = fmaf(bfhi(g), Wout[(2 * k2 + 1) * 16 + pe], acc);
    }
    out[(size_t)n * 16 + pe] = acc;
}

extern "C" void kernel_launch(void* const* d_in, const int* in_sizes, int n_in,
                              void* d_out, int out_size, void* d_ws, size_t ws_size,
                              hipStream_t stream) {
    const int*   x_type     = (const int*)  d_in[0];
    const float* x_feat     = (const float*)d_in[1];
    const int*   edge_index = (const int*)  d_in[2];
    const float* edge_attr  = (const float*)d_in[3];
    const float* type_embed = (const float*)d_in[4];
    const float* featW      = (const float*)d_in[5];
    const float* featb      = (const float*)d_in[6];
    const float* edgeW      = (const float*)d_in[7];
    const float* edgeb      = (const float*)d_in[8];
    const float* W1         = (const float*)d_in[9];
    const float* b1         = (const float*)d_in[10];
    const float* W2         = (const float*)d_in[11];
    const float* b2         = (const float*)d_in[12];
    const float* eps        = (const float*)d_in[13];
    const float* Wout       = (const float*)d_in[14];
    const float* bout       = (const float*)d_in[15];

    const int N = in_sizes[0];
    const int E = in_sizes[2] / 2;
    const int L = in_sizes[13];
    const int N64 = (N + 63) & ~63;        // padded node buffers
    const int NB  = (N + NPB - 1) / NPB;   // 196 buckets
    const int M   = NB * NCH;              // histogram matrix size

    const int* srcIdx = edge_index;
    const int* dstIdx = edge_index + E;

    auto align256 = [](size_t x) { return (x + 255) & ~(size_t)255; };
    char* p = (char*)d_ws;
    ushort16* h_buf  = (ushort16*)p;           p += align256((size_t)N64 * HDIM * 2);
    ushort16* z_buf  = (ushort16*)p;           p += align256((size_t)N64 * HDIM * 2);
    int*   row_ptr   = (int*)p;                p += align256((size_t)(N + 1) * 4);
    int*   histM     = (int*)p;                p += align256((size_t)M * 4);
    int*   Fscan     = (int*)p;                p += align256((size_t)M * 4);
    int*   partials  = (int*)p;                p += align256(1024 * 4);
    int*   offsets   = (int*)p;                p += align256(1024 * 4);
    int4*  tmp       = (int4*)p;               p += align256((size_t)E * 16);
    int4*  adj       = (int4*)p;               p += align256((size_t)E * 16);
    ushort16* Wb1t   = (ushort16*)p;           p += align256((size_t)L * HDIM * HDIM * 2);
    ushort16* Wb2t   = (ushort16*)p;           p += align256((size_t)L * HDIM * HDIM * 2);
    (void)ws_size;

    // ---- CSR build: counting sort, no global atomics ----
    hist_kernel<<<NCH, 256, 0, stream>>>(dstIdx, histM, E, NB);
    const int pblocks = (M + 255) / 256;            // 784
    partial_kernel<<<pblocks, 256, 0, stream>>>(histM, partials, M);
    scan_partials_kernel<<<1, 1024, 0, stream>>>(partials, offsets, pblocks);
    excl_out_kernel<<<pblocks, 256, 0, stream>>>(histM, offsets, Fscan, M);
    chunk_scatter_kernel<<<NCH, 256, 0, stream>>>(srcIdx, dstIdx, edge_attr, Fscan, tmp, E, NB);
    bucket_sort_kernel<<<NB, 256, 0, stream>>>(tmp, Fscan, row_ptr, adj, E, NB, N);

    const int wtotal = L * HDIM * HDIM;
    prep_weights<<<(wtotal + 255) / 256, 256, 0, stream>>>(W1, W2, Wb1t, Wb2t, wtotal);

    embed_kernel<<<((size_t)N * HDIM + 255) / 256, 256, 0, stream>>>(
        x_type, x_feat, type_embed, featW, featb, h_buf, N);

    const int mlp_blocks = N64 / 16;        // 16 rows per block, 2 waves each
    for (int l = 0; l < L; ++l) {
        agg_kernel<<<(N + 1) / 2, 128, 0, stream>>>(
            (const uint32*)h_buf, row_ptr, adj, edgeW, edgeb, eps, l,
            (uint32*)z_buf, N);
        mlp_mfma<<<mlp_blocks, 128, 0, stream>>>(
            z_buf, Wb1t + (size_t)l * HDIM * HDIM, b1 + (size_t)l * HDIM,
            Wb2t + (size_t)l * HDIM * HDIM, b2 + (size_t)l * HDIM, h_buf, N);
    }

    out_kernel<<<((size_t)N * 16 + 255) / 256, 256, 0, stream>>>(
        (const uint32*)h_buf, Wout, bout, (float*)d_out, N);
}

// Round 14
// 280.275 us; speedup vs baseline: 1.0692x; 1.0692x over previous
//
#include <hip/hip_runtime.h>
#include <hip/hip_bf16.h>

// ---------------------------------------------------------------------------
// EncoderGNN: 3-layer GINE encoder, N=50000, E=800000, H=128.
// Round 14: revert r13 (both changes lost). = r12 config: counting-sort CSR,
// r6 agg (1 wave/node, scalarized, unroll x8, VGPR 28), 1-wave/16-row MFMA
// MLP. New: out_kernel stages h rows in LDS (kills 16x redundant row reads).
// ---------------------------------------------------------------------------

#define HDIM 128
#define NCH 1024          // histogram chunks
#define NPB 256           // nodes per bucket

typedef unsigned int uint32;
typedef unsigned short ushort16;
typedef __attribute__((ext_vector_type(8))) short short8;
typedef __attribute__((ext_vector_type(4))) float f32x4;
typedef __attribute__((ext_vector_type(2))) float f32x2;

__device__ __forceinline__ ushort16 f2bf(float f) {
    uint32 u = __float_as_uint(f);
    u += 0x7fff + ((u >> 16) & 1);      // round-to-nearest-even
    return (ushort16)(u >> 16);
}
__device__ __forceinline__ float bflo(uint32 g) { return __uint_as_float(g << 16); }
__device__ __forceinline__ float bfhi(uint32 g) { return __uint_as_float(g & 0xffff0000u); }

// ---------------- CSR build: counting sort ----------------
__global__ __launch_bounds__(256) void hist_kernel(const int* __restrict__ dstIdx,
                                                   int* __restrict__ histM, int E, int NB) {
    __shared__ int hist[256];
    const int b = blockIdx.x;
    for (int j = threadIdx.x; j < NB; j += 256) hist[j] = 0;
    __syncthreads();
    const int epb = (E + NCH - 1) / NCH;
    const int e0 = b * epb, e1 = min(e0 + epb, E);
    for (int e = e0 + threadIdx.x; e < e1; e += 256)
        atomicAdd(&hist[dstIdx[e] >> 8], 1);
    __syncthreads();
    for (int j = threadIdx.x; j < NB; j += 256)
        histM[j * NCH + b] = hist[j];
}

__global__ __launch_bounds__(256) void partial_kernel(const int* __restrict__ F,
                                                      int* __restrict__ partials, int M) {
    __shared__ int red[256];
    int i = blockIdx.x * 256 + threadIdx.x;
    red[threadIdx.x] = (i < M) ? F[i] : 0;
    __syncthreads();
#pragma unroll
    for (int off = 128; off > 0; off >>= 1) {
        if (threadIdx.x < off) red[threadIdx.x] += red[threadIdx.x + off];
        __syncthreads();
    }
    if (threadIdx.x == 0) partials[blockIdx.x] = red[0];
}

__global__ __launch_bounds__(1024) void scan_partials_kernel(const int* __restrict__ partials,
                                                             int* __restrict__ offsets, int nb) {
    __shared__ int buf[1024];
    int tid = threadIdx.x;
    int v0 = (tid < nb) ? partials[tid] : 0;
    buf[tid] = v0;
    __syncthreads();
#pragma unroll
    for (int off = 1; off < 1024; off <<= 1) {
        int v = (tid >= off) ? buf[tid - off] : 0;
        __syncthreads();
        buf[tid] += v;
        __syncthreads();
    }
    if (tid < nb) offsets[tid] = buf[tid] - v0;   // exclusive
}

__global__ __launch_bounds__(256) void excl_out_kernel(const int* __restrict__ F,
                                                       const int* __restrict__ offsets,
                                                       int* __restrict__ Fscan, int M) {
    __shared__ int buf[256];
    int tid = threadIdx.x;
    int i = blockIdx.x * 256 + tid;
    int v = (i < M) ? F[i] : 0;
    buf[tid] = v;
    __syncthreads();
#pragma unroll
    for (int off = 1; off < 256; off <<= 1) {
        int t = (tid >= off) ? buf[tid - off] : 0;
        __syncthreads();
        buf[tid] += t;
        __syncthreads();
    }
    if (i < M) Fscan[i] = buf[tid] - v + offsets[blockIdx.x];
}

__global__ __launch_bounds__(256) void chunk_scatter_kernel(
        const int* __restrict__ srcIdx, const int* __restrict__ dstIdx,
        const float* __restrict__ edge_attr, const int* __restrict__ Fscan,
        int4* __restrict__ tmp, int E, int NB) {
    __shared__ int cur[256];
    const int b = blockIdx.x;
    for (int j = threadIdx.x; j < NB; j += 256) cur[j] = Fscan[j * NCH + b];
    __syncthreads();
    const int epb = (E + NCH - 1) / NCH;
    const int e0 = b * epb, e1 = min(e0 + epb, E);
    for (int e = e0 + threadIdx.x; e < e1; e += 256) {
        int d = dstIdx[e];
        int r = atomicAdd(&cur[d >> 8], 1);
        float4 ea = *(const float4*)(edge_attr + (size_t)e * 4);
        int4 rec;
        rec.x = srcIdx[e];
        rec.y = (int)(((uint32)f2bf(ea.y) << 16) | (uint32)f2bf(ea.x));
        rec.z = (int)(((uint32)f2bf(ea.w) << 16) | (uint32)f2bf(ea.z));
        rec.w = d;
        tmp[r] = rec;
    }
}

__global__ __launch_bounds__(256) void bucket_sort_kernel(
        const int4* __restrict__ tmp, const int* __restrict__ Fscan,
        int* __restrict__ row_ptr, int4* __restrict__ adj, int E, int NB, int N) {
    __shared__ int cnt[256];
    __shared__ int cur[256];
    const int bkt = blockIdx.x;
    const int tid = threadIdx.x;
    const int base = Fscan[bkt * NCH];
    const int endb = (bkt + 1 < NB) ? Fscan[(bkt + 1) * NCH] : E;

    cnt[tid] = 0;
    __syncthreads();
    for (int i = base + tid; i < endb; i += 256)
        atomicAdd(&cnt[tmp[i].w & 255], 1);
    __syncthreads();
    int orig = cnt[tid];
#pragma unroll
    for (int off = 1; off < 256; off <<= 1) {
        int v = (tid >= off) ? cnt[tid - off] : 0;
        __syncthreads();
        cnt[tid] += v;
        __syncthreads();
    }
    int excl = cnt[tid] - orig;
    int node = bkt * NPB + tid;
    if (node <= N) row_ptr[node] = base + excl;
    cur[tid] = base + excl;
    __syncthreads();
    for (int i = base + tid; i < endb; i += 256) {
        int4 rec = tmp[i];
        int pos = atomicAdd(&cur[rec.w & 255], 1);
        adj[pos] = rec;
    }
}

// ---------------- weight prep: bf16 + transpose (once per call) ----------------
__global__ void prep_weights(const float* __restrict__ W1, const float* __restrict__ W2,
                             ushort16* __restrict__ Wb1t, ushort16* __restrict__ Wb2t, int total) {
    int idx = blockIdx.x * 256 + threadIdx.x;
    if (idx >= total) return;
    int l = idx >> 14;
    int rem = idx & 16383;
    int n = rem >> 7, k = rem & 127;
    size_t src = (size_t)l * 16384 + (size_t)k * 128 + n;
    size_t dst = (size_t)l * 16384 + (size_t)n * 128 + k;
    Wb1t[dst] = f2bf(W1[src]);
    Wb2t[dst] = f2bf(W2[src]);
}

// ---------------- node embedding (writes bf16 h) ----------------
__global__ void embed_kernel(const int* __restrict__ x_type, const float* __restrict__ x_feat,
                             const float* __restrict__ type_embed, const float* __restrict__ featW,
                             const float* __restrict__ featb, ushort16* __restrict__ h, int N) {
    int idx = blockIdx.x * 256 + threadIdx.x;
    int n = idx >> 7, c = idx & 127;
    if (n >= N) return;
    int t = x_type[n];
    float acc = type_embed[(size_t)t * HDIM + c] + featb[c];
#pragma unroll
    for (int k = 0; k < 7; ++k)
        acc = fmaf(x_feat[(size_t)n * 7 + k], featW[(size_t)k * HDIM + c], acc);
    h[(size_t)n * HDIM + c] = f2bf(acc);
}

// ---------------- aggregation: r6 form (best measured), unroll x8 ----------------
__global__ __launch_bounds__(128) void agg_kernel(
        const uint32* __restrict__ hq,       // [N][64] packed bf16x2
        const int* __restrict__ row_ptr,
        const int4* __restrict__ adj,        // 16B records (uniform per wave)
        const float* __restrict__ edgeW, const float* __restrict__ edgeb,
        const float* __restrict__ eps, int l, uint32* __restrict__ zq, int N) {
    const int node = blockIdx.x * 2 + (threadIdx.x >> 6);
    const int lane = threadIdx.x & 63;
    if (node >= N) return;
    const int c0 = 2 * lane;
    const f32x2 w0 = {edgeW[c0],       edgeW[c0 + 1]};
    const f32x2 w1 = {edgeW[128 + c0], edgeW[128 + c0 + 1]};
    const f32x2 w2 = {edgeW[256 + c0], edgeW[256 + c0 + 1]};
    const f32x2 w3 = {edgeW[384 + c0], edgeW[384 + c0 + 1]};
    const f32x2 eb = {edgeb[c0],       edgeb[c0 + 1]};

    const int beg = __builtin_amdgcn_readfirstlane(row_ptr[node]);
    const int end = __builtin_amdgcn_readfirstlane(row_ptr[node + 1]);

    const uint32 gs = hq[(size_t)node * 64 + lane];   // self-term early

    f32x2 accA = {0.f, 0.f}, accB = {0.f, 0.f};

#define EDGE(Q, G, ACC) {                                                     \
        f32x2 e = eb;                                                         \
        e += bflo((uint32)(Q).y) * w0;                                        \
        e += bfhi((uint32)(Q).y) * w1;                                        \
        e += bflo((uint32)(Q).z) * w2;                                        \
        e += bfhi((uint32)(Q).z) * w3;                                        \
        ACC.x += fmaxf(bflo(G) + e.x, 0.f);                                   \
        ACC.y += fmaxf(bfhi(G) + e.y, 0.f);                                   \
    }

    int i = beg;
    for (; i + 8 <= end; i += 8) {
        int4 q0 = adj[i + 0], q1 = adj[i + 1], q2 = adj[i + 2], q3 = adj[i + 3];
        int4 q4 = adj[i + 4], q5 = adj[i + 5], q6 = adj[i + 6], q7 = adj[i + 7];
        uint32 g0 = hq[(size_t)q0.x * 64 + lane];
        uint32 g1 = hq[(size_t)q1.x * 64 + lane];
        uint32 g2 = hq[(size_t)q2.x * 64 + lane];
        uint32 g3 = hq[(size_t)q3.x * 64 + lane];
        uint32 g4 = hq[(size_t)q4.x * 64 + lane];
        uint32 g5 = hq[(size_t)q5.x * 64 + lane];
        uint32 g6 = hq[(size_t)q6.x * 64 + lane];
        uint32 g7 = hq[(size_t)q7.x * 64 + lane];
        EDGE(q0, g0, accA); EDGE(q1, g1, accB);
        EDGE(q2, g2, accA); EDGE(q3, g3, accB);
        EDGE(q4, g4, accA); EDGE(q5, g5, accB);
        EDGE(q6, g6, accA); EDGE(q7, g7, accB);
    }
    for (; i + 4 <= end; i += 4) {
        int4 q0 = adj[i + 0], q1 = adj[i + 1], q2 = adj[i + 2], q3 = adj[i + 3];
        uint32 g0 = hq[(size_t)q0.x * 64 + lane];
        uint32 g1 = hq[(size_t)q1.x * 64 + lane];
        uint32 g2 = hq[(size_t)q2.x * 64 + lane];
        uint32 g3 = hq[(size_t)q3.x * 64 + lane];
        EDGE(q0, g0, accA); EDGE(q1, g1, accB);
        EDGE(q2, g2, accA); EDGE(q3, g3, accB);
    }
    for (; i < end; ++i) {
        int4 q = adj[i];
        uint32 g = hq[(size_t)q.x * 64 + lane];
        EDGE(q, g, accA);
    }
#undef EDGE

    const float ep = 1.0f + eps[l];
    float zl = fmaf(ep, bflo(gs), accA.x + accB.x);
    float zh = fmaf(ep, bfhi(gs), accA.y + accB.y);
    zq[(size_t)node * 64 + lane] = ((uint32)f2bf(zh) << 16) | (uint32)f2bf(zl);
}

// ---------------- MFMA MLP, operand-swapped, 1 wave / 16 rows per block ----------------
#define T_STRIDE 136   // shorts; 272B rows: 16B-aligned for b128 reads
__global__ __launch_bounds__(64) void mlp_mfma(
        const ushort16* __restrict__ zq,     // [N64][128] bf16
        const ushort16* __restrict__ Wb1t,   // [128 n][128 k] bf16
        const float* __restrict__ b1,
        const ushort16* __restrict__ Wb2t,
        const float* __restrict__ b2,
        ushort16* __restrict__ h_out, int N) {
    __shared__ ushort16 t_lds[16 * T_STRIDE];
    const int lane = threadIdx.x & 63;
    const int c = lane & 15, g = lane >> 4;
    const int wrow0 = blockIdx.x * 16;            // node-tile base

    // ---- GEMM1: t^T = W1^T @ z^T ----
    const ushort16* zrow = zq + (size_t)(wrow0 + c) * HDIM + g * 8;
    short8 bf[4];
#pragma unroll
    for (int kk = 0; kk < 4; ++kk)
        bf[kk] = *(const short8*)(zrow + kk * 32);

    f32x4 acc[8];
#pragma unroll
    for (int n = 0; n < 8; ++n) {
        float4 bb = *(const float4*)(b1 + n * 16 + g * 4);
        acc[n] = (f32x4){bb.x, bb.y, bb.z, bb.w};
    }
#pragma unroll
    for (int kk = 0; kk < 4; ++kk) {
#pragma unroll
        for (int n = 0; n < 8; ++n) {
            short8 af = *(const short8*)(Wb1t + (size_t)(n * 16 + c) * HDIM + kk * 32 + g * 8);
            acc[n] = __builtin_amdgcn_mfma_f32_16x16x32_bf16(af, bf[kk], acc[n], 0, 0, 0);
        }
    }
#pragma unroll
    for (int n = 0; n < 8; ++n) {
        ushort4 u;
        u.x = f2bf(fmaxf(acc[n][0], 0.f));
        u.y = f2bf(fmaxf(acc[n][1], 0.f));
        u.z = f2bf(fmaxf(acc[n][2], 0.f));
        u.w = f2bf(fmaxf(acc[n][3], 0.f));
        *(ushort4*)(&t_lds[c * T_STRIDE + n * 16 + g * 4]) = u;
    }
    __syncthreads();

    // ---- GEMM2: h^T = W2^T @ t^T ----
    short8 bf2[4];
#pragma unroll
    for (int kk = 0; kk < 4; ++kk)
        bf2[kk] = *(const short8*)(&t_lds[c * T_STRIDE + kk * 32 + g * 8]);

    f32x4 acc2[8];
#pragma unroll
    for (int n = 0; n < 8; ++n) {
        float4 bb = *(const float4*)(b2 + n * 16 + g * 4);
        acc2[n] = (f32x4){bb.x, bb.y, bb.z, bb.w};
    }
#pragma unroll
    for (int kk = 0; kk < 4; ++kk) {
#pragma unroll
        for (int n = 0; n < 8; ++n) {
            short8 af = *(const short8*)(Wb2t + (size_t)(n * 16 + c) * HDIM + kk * 32 + g * 8);
            acc2[n] = __builtin_amdgcn_mfma_f32_16x16x32_bf16(af, bf2[kk], acc2[n], 0, 0, 0);
        }
    }
    if (wrow0 + c < N) {
#pragma unroll
        for (int n = 0; n < 8; ++n) {
            ushort4 u;
            u.x = f2bf(fmaxf(acc2[n][0], 0.f));
            u.y = f2bf(fmaxf(acc2[n][1], 0.f));
            u.z = f2bf(fmaxf(acc2[n][2], 0.f));
            u.w = f2bf(fmaxf(acc2[n][3], 0.f));
            *(ushort4*)(h_out + (size_t)(wrow0 + c) * HDIM + n * 16 + g * 4) = u;
        }
    }
}

// ---------------- output projection: LDS-staged h rows ----------------
// Block = 256 thd over 16 nodes; stage 16 x 128 bf16 rows once in LDS, then
// thread (n,pe) reduces from LDS (no 16x redundant global row reads).
__global__ __launch_bounds__(256) void out_kernel(
        const uint32* __restrict__ hq, const float* __restrict__ Wout,
        const float* __restrict__ bout, float* __restrict__ out, int N) {
    __shared__ uint32 rows[16][64];
    const int tid = threadIdx.x;
    const int n0 = blockIdx.x * 16;
    // stage: 256 threads cover 16 rows x 64 uint32 in 4 steps
#pragma unroll
    for (int s = 0; s < 4; ++s) {
        int idx = tid + s * 256;           // 0..1023
        int r = idx >> 6, cc = idx & 63;
        int n = n0 + r;
        rows[r][cc] = (n < N) ? hq[(size_t)n * 64 + cc] : 0u;
    }
    __syncthreads();
    const int r = tid >> 4, pe = tid & 15;
    const int n = n0 + r;
    if (n >= N) return;
    float acc = bout[pe];
#pragma unroll 8
    for (int k2 = 0; k2 < 64; ++k2) {
        uint32 g = rows[r][k2];
        acc = fmaf(bflo(g), Wout[(2 * k2) * 16 + pe], acc);
        acc = fmaf(bfhi(g), Wout[(2 * k2 + 1) * 16 + pe], acc);
    }
    out[(size_t)n * 16 + pe] = acc;
}

extern "C" void kernel_launch(void* const* d_in, const int* in_sizes, int n_in,
                              void* d_out, int out_size, void* d_ws, size_t ws_size,
                              hipStream_t stream) {
    const int*   x_type     = (const int*)  d_in[0];
    const float* x_feat     = (const float*)d_in[1];
    const int*   edge_index = (const int*)  d_in[2];
    const float* edge_attr  = (const float*)d_in[3];
    const float* type_embed = (const float*)d_in[4];
    const float* featW      = (const float*)d_in[5];
    const float* featb      = (const float*)d_in[6];
    const float* edgeW      = (const float*)d_in[7];
    const float* edgeb      = (const float*)d_in[8];
    const float* W1         = (const float*)d_in[9];
    const float* b1         = (const float*)d_in[10];
    const float* W2         = (const float*)d_in[11];
    const float* b2         = (const float*)d_in[12];
    const float* eps        = (const float*)d_in[13];
    const float* Wout       = (const float*)d_in[14];
    const float* bout       = (const float*)d_in[15];

    const int N = in_sizes[0];
    const int E = in_sizes[2] / 2;
    const int L = in_sizes[13];
    const int N64 = (N + 63) & ~63;        // padded node buffers
    const int NB  = (N + NPB - 1) / NPB;   // 196 buckets
    const int M   = NB * NCH;              // histogram matrix size

    const int* srcIdx = edge_index;
    const int* dstIdx = edge_index + E;

    auto align256 = [](size_t x) { return (x + 255) & ~(size_t)255; };
    char* p = (char*)d_ws;
    ushort16* h_buf  = (ushort16*)p;           p += align256((size_t)N64 * HDIM * 2);
    ushort16* z_buf  = (ushort16*)p;           p += align256((size_t)N64 * HDIM * 2);
    int*   row_ptr   = (int*)p;                p += align256((size_t)(N + 1) * 4);
    int*   histM     = (int*)p;                p += align256((size_t)M * 4);
    int*   Fscan     = (int*)p;                p += align256((size_t)M * 4);
    int*   partials  = (int*)p;                p += align256(1024 * 4);
    int*   offsets   = (int*)p;                p += align256(1024 * 4);
    int4*  tmp       = (int4*)p;               p += align256((size_t)E * 16);
    int4*  adj       = (int4*)p;               p += align256((size_t)E * 16);
    ushort16* Wb1t   = (ushort16*)p;           p += align256((size_t)L * HDIM * HDIM * 2);
    ushort16* Wb2t   = (ushort16*)p;           p += align256((size_t)L * HDIM * HDIM * 2);
    (void)ws_size;

    // ---- CSR build: counting sort, no global atomics ----
    hist_kernel<<<NCH, 256, 0, stream>>>(dstIdx, histM, E, NB);
    const int pblocks = (M + 255) / 256;            // 784
    partial_kernel<<<pblocks, 256, 0, stream>>>(histM, partials, M);
    scan_partials_kernel<<<1, 1024, 0, stream>>>(partials, offsets, pblocks);
    excl_out_kernel<<<pblocks, 256, 0, stream>>>(histM, offsets, Fscan, M);
    chunk_scatter_kernel<<<NCH, 256, 0, stream>>>(srcIdx, dstIdx, edge_attr, Fscan, tmp, E, NB);
    bucket_sort_kernel<<<NB, 256, 0, stream>>>(tmp, Fscan, row_ptr, adj, E, NB, N);

    const int wtotal = L * HDIM * HDIM;
    prep_weights<<<(wtotal + 255) / 256, 256, 0, stream>>>(W1, W2, Wb1t, Wb2t, wtotal);

    embed_kernel<<<((size_t)N * HDIM + 255) / 256, 256, 0, stream>>>(
        x_type, x_feat, type_embed, featW, featb, h_buf, N);

    const int mlp_blocks = (N + 15) / 16;   // 3125 one-wave blocks
    for (int l = 0; l < L; ++l) {
        agg_kernel<<<(N + 1) / 2, 128, 0, stream>>>(
            (const uint32*)h_buf, row_ptr, adj, edgeW, edgeb, eps, l,
            (uint32*)z_buf, N);
        mlp_mfma<<<mlp_blocks, 64, 0, stream>>>(
            z_buf, Wb1t + (size_t)l * HDIM * HDIM, b1 + (size_t)l * HDIM,
            Wb2t + (size_t)l * HDIM * HDIM, b2 + (size_t)l * HDIM, h_buf, N);
    }

    out_kernel<<<(N + 15) / 16, 256, 0, stream>>>(
        (const uint32*)h_buf, Wout, bout, (float*)d_out, N);
}

// Round 15
// 280.124 us; speedup vs baseline: 1.0698x; 1.0005x over previous
//
#include <hip/hip_runtime.h>
#include <hip/hip_bf16.h>

// ---------------------------------------------------------------------------
// EncoderGNN: 3-layer GINE encoder, N=50000, E=800000, H=128.
// Round 15: dispatch consolidation (15 -> 12), hot kernels untouched.
//  - pre_kernel = hist || prep_weights || embed (independent; one dispatch)
//  - partial_scan_kernel = partial + scan_partials (last-block-done pattern)
//  - excl_out widened to 1024-thd blocks to match
// agg = r6 form (1 wave/node, scalarized, unroll x8); mlp = r12 1-wave/16-row
// MFMA; counting-sort CSR; LDS-staged out_kernel.
// ---------------------------------------------------------------------------

#define HDIM 128
#define NCH 1024          // histogram chunks
#define NPB 256           // nodes per bucket

typedef unsigned int uint32;
typedef unsigned short ushort16;
typedef __attribute__((ext_vector_type(8))) short short8;
typedef __attribute__((ext_vector_type(4))) float f32x4;
typedef __attribute__((ext_vector_type(2))) float f32x2;

__device__ __forceinline__ ushort16 f2bf(float f) {
    uint32 u = __float_as_uint(f);
    u += 0x7fff + ((u >> 16) & 1);      // round-to-nearest-even
    return (ushort16)(u >> 16);
}
__device__ __forceinline__ float bflo(uint32 g) { return __uint_as_float(g << 16); }
__device__ __forceinline__ float bfhi(uint32 g) { return __uint_as_float(g & 0xffff0000u); }

// ---------------- fused preprocessing: hist || prep_weights || embed ----------------
__global__ __launch_bounds__(256) void pre_kernel(
        const int* __restrict__ dstIdx, int* __restrict__ histM, int E, int NB,
        const float* __restrict__ W1, const float* __restrict__ W2,
        ushort16* __restrict__ Wb1t, ushort16* __restrict__ Wb2t, int wtotal,
        const int* __restrict__ x_type, const float* __restrict__ x_feat,
        const float* __restrict__ type_embed, const float* __restrict__ featW,
        const float* __restrict__ featb, ushort16* __restrict__ h, int N,
        int* __restrict__ done, int prepB) {
    __shared__ int hist[256];
    const int b = blockIdx.x;
    if (b == 0 && threadIdx.x == 0) *done = 0;    // reset for partial_scan

    if (b < NCH) {
        // ---- histogram chunk b ----
        for (int j = threadIdx.x; j < NB; j += 256) hist[j] = 0;
        __syncthreads();
        const int epb = (E + NCH - 1) / NCH;
        const int e0 = b * epb, e1 = min(e0 + epb, E);
        for (int e = e0 + threadIdx.x; e < e1; e += 256)
            atomicAdd(&hist[dstIdx[e] >> 8], 1);
        __syncthreads();
        for (int j = threadIdx.x; j < NB; j += 256)
            histM[j * NCH + b] = hist[j];
    } else if (b < NCH + prepB) {
        // ---- weight prep ----
        int idx = (b - NCH) * 256 + threadIdx.x;
        if (idx < wtotal) {
            int l = idx >> 14;
            int rem = idx & 16383;
            int n = rem >> 7, k = rem & 127;
            size_t src = (size_t)l * 16384 + (size_t)k * 128 + n;
            size_t dst = (size_t)l * 16384 + (size_t)n * 128 + k;
            Wb1t[dst] = f2bf(W1[src]);
            Wb2t[dst] = f2bf(W2[src]);
        }
    } else {
        // ---- node embedding ----
        int idx = (b - NCH - prepB) * 256 + threadIdx.x;
        int n = idx >> 7, c = idx & 127;
        if (n < N) {
            int t = x_type[n];
            float acc = type_embed[(size_t)t * HDIM + c] + featb[c];
#pragma unroll
            for (int k = 0; k < 7; ++k)
                acc = fmaf(x_feat[(size_t)n * 7 + k], featW[(size_t)k * HDIM + c], acc);
            h[(size_t)n * HDIM + c] = f2bf(acc);
        }
    }
}

// ---------------- partial sums + top-level scan (last-block-done) ----------------
__global__ __launch_bounds__(1024) void partial_scan_kernel(
        const int* __restrict__ F, int* __restrict__ partials,
        int* __restrict__ offsets, int* __restrict__ done, int M, int nblocks) {
    __shared__ int red[1024];
    __shared__ int lastFlag;
    const int tid = threadIdx.x;
    int i = blockIdx.x * 1024 + tid;
    red[tid] = (i < M) ? F[i] : 0;
    __syncthreads();
#pragma unroll
    for (int off = 512; off > 0; off >>= 1) {
        if (tid < off) red[tid] += red[tid + off];
        __syncthreads();
    }
    if (tid == 0) {
        partials[blockIdx.x] = red[0];
        __threadfence();
        int old = atomicAdd(done, 1);
        lastFlag = (old == nblocks - 1);
    }
    __syncthreads();
    if (lastFlag) {
        // device-scope atomic loads guarantee cross-XCD visibility
        int v = (tid < nblocks) ? atomicAdd(&partials[tid], 0) : 0;
        red[tid] = v;
        __syncthreads();
#pragma unroll
        for (int off = 1; off < 1024; off <<= 1) {
            int t = (tid >= off) ? red[tid - off] : 0;
            __syncthreads();
            red[tid] += t;
            __syncthreads();
        }
        if (tid < nblocks) offsets[tid] = red[tid] - v;   // exclusive
    }
}

// ---------------- per-1024-block exclusive scan output ----------------
__global__ __launch_bounds__(1024) void excl_out_kernel(const int* __restrict__ F,
                                                        const int* __restrict__ offsets,
                                                        int* __restrict__ Fscan, int M) {
    __shared__ int buf[1024];
    const int tid = threadIdx.x;
    int i = blockIdx.x * 1024 + tid;
    int v = (i < M) ? F[i] : 0;
    buf[tid] = v;
    __syncthreads();
#pragma unroll
    for (int off = 1; off < 1024; off <<= 1) {
        int t = (tid >= off) ? buf[tid - off] : 0;
        __syncthreads();
        buf[tid] += t;
        __syncthreads();
    }
    if (i < M) Fscan[i] = buf[tid] - v + offsets[blockIdx.x];
}

__global__ __launch_bounds__(256) void chunk_scatter_kernel(
        const int* __restrict__ srcIdx, const int* __restrict__ dstIdx,
        const float* __restrict__ edge_attr, const int* __restrict__ Fscan,
        int4* __restrict__ tmp, int E, int NB) {
    __shared__ int cur[256];
    const int b = blockIdx.x;
    for (int j = threadIdx.x; j < NB; j += 256) cur[j] = Fscan[j * NCH + b];
    __syncthreads();
    const int epb = (E + NCH - 1) / NCH;
    const int e0 = b * epb, e1 = min(e0 + epb, E);
    for (int e = e0 + threadIdx.x; e < e1; e += 256) {
        int d = dstIdx[e];
        int r = atomicAdd(&cur[d >> 8], 1);
        float4 ea = *(const float4*)(edge_attr + (size_t)e * 4);
        int4 rec;
        rec.x = srcIdx[e];
        rec.y = (int)(((uint32)f2bf(ea.y) << 16) | (uint32)f2bf(ea.x));
        rec.z = (int)(((uint32)f2bf(ea.w) << 16) | (uint32)f2bf(ea.z));
        rec.w = d;
        tmp[r] = rec;
    }
}

__global__ __launch_bounds__(256) void bucket_sort_kernel(
        const int4* __restrict__ tmp, const int* __restrict__ Fscan,
        int* __restrict__ row_ptr, int4* __restrict__ adj, int E, int NB, int N) {
    __shared__ int cnt[256];
    __shared__ int cur[256];
    const int bkt = blockIdx.x;
    const int tid = threadIdx.x;
    const int base = Fscan[bkt * NCH];
    const int endb = (bkt + 1 < NB) ? Fscan[(bkt + 1) * NCH] : E;

    cnt[tid] = 0;
    __syncthreads();
    for (int i = base + tid; i < endb; i += 256)
        atomicAdd(&cnt[tmp[i].w & 255], 1);
    __syncthreads();
    int orig = cnt[tid];
#pragma unroll
    for (int off = 1; off < 256; off <<= 1) {
        int v = (tid >= off) ? cnt[tid - off] : 0;
        __syncthreads();
        cnt[tid] += v;
        __syncthreads();
    }
    int excl = cnt[tid] - orig;
    int node = bkt * NPB + tid;
    if (node <= N) row_ptr[node] = base + excl;
    cur[tid] = base + excl;
    __syncthreads();
    for (int i = base + tid; i < endb; i += 256) {
        int4 rec = tmp[i];
        int pos = atomicAdd(&cur[rec.w & 255], 1);
        adj[pos] = rec;
    }
}

// ---------------- aggregation: r6 form (best measured), unroll x8 ----------------
__global__ __launch_bounds__(128) void agg_kernel(
        const uint32* __restrict__ hq,       // [N][64] packed bf16x2
        const int* __restrict__ row_ptr,
        const int4* __restrict__ adj,        // 16B records (uniform per wave)
        const float* __restrict__ edgeW, const float* __restrict__ edgeb,
        const float* __restrict__ eps, int l, uint32* __restrict__ zq, int N) {
    const int node = blockIdx.x * 2 + (threadIdx.x >> 6);
    const int lane = threadIdx.x & 63;
    if (node >= N) return;
    const int c0 = 2 * lane;
    const f32x2 w0 = {edgeW[c0],       edgeW[c0 + 1]};
    const f32x2 w1 = {edgeW[128 + c0], edgeW[128 + c0 + 1]};
    const f32x2 w2 = {edgeW[256 + c0], edgeW[256 + c0 + 1]};
    const f32x2 w3 = {edgeW[384 + c0], edgeW[384 + c0 + 1]};
    const f32x2 eb = {edgeb[c0],       edgeb[c0 + 1]};

    const int beg = __builtin_amdgcn_readfirstlane(row_ptr[node]);
    const int end = __builtin_amdgcn_readfirstlane(row_ptr[node + 1]);

    const uint32 gs = hq[(size_t)node * 64 + lane];   // self-term early

    f32x2 accA = {0.f, 0.f}, accB = {0.f, 0.f};

#define EDGE(Q, G, ACC) {                                                     \
        f32x2 e = eb;                                                         \
        e += bflo((uint32)(Q).y) * w0;                                        \
        e += bfhi((uint32)(Q).y) * w1;                                        \
        e += bflo((uint32)(Q).z) * w2;                                        \
        e += bfhi((uint32)(Q).z) * w3;                                        \
        ACC.x += fmaxf(bflo(G) + e.x, 0.f);                                   \
        ACC.y += fmaxf(bfhi(G) + e.y, 0.f);                                   \
    }

    int i = beg;
    for (; i + 8 <= end; i += 8) {
        int4 q0 = adj[i + 0], q1 = adj[i + 1], q2 = adj[i + 2], q3 = adj[i + 3];
        int4 q4 = adj[i + 4], q5 = adj[i + 5], q6 = adj[i + 6], q7 = adj[i + 7];
        uint32 g0 = hq[(size_t)q0.x * 64 + lane];
        uint32 g1 = hq[(size_t)q1.x * 64 + lane];
        uint32 g2 = hq[(size_t)q2.x * 64 + lane];
        uint32 g3 = hq[(size_t)q3.x * 64 + lane];
        uint32 g4 = hq[(size_t)q4.x * 64 + lane];
        uint32 g5 = hq[(size_t)q5.x * 64 + lane];
        uint32 g6 = hq[(size_t)q6.x * 64 + lane];
        uint32 g7 = hq[(size_t)q7.x * 64 + lane];
        EDGE(q0, g0, accA); EDGE(q1, g1, accB);
        EDGE(q2, g2, accA); EDGE(q3, g3, accB);
        EDGE(q4, g4, accA); EDGE(q5, g5, accB);
        EDGE(q6, g6, accA); EDGE(q7, g7, accB);
    }
    for (; i + 4 <= end; i += 4) {
        int4 q0 = adj[i + 0], q1 = adj[i + 1], q2 = adj[i + 2], q3 = adj[i + 3];
        uint32 g0 = hq[(size_t)q0.x * 64 + lane];
        uint32 g1 = hq[(size_t)q1.x * 64 + lane];
        uint32 g2 = hq[(size_t)q2.x * 64 + lane];
        uint32 g3 = hq[(size_t)q3.x * 64 + lane];
        EDGE(q0, g0, accA); EDGE(q1, g1, accB);
        EDGE(q2, g2, accA); EDGE(q3, g3, accB);
    }
    for (; i < end; ++i) {
        int4 q = adj[i];
        uint32 g = hq[(size_t)q.x * 64 + lane];
        EDGE(q, g, accA);
    }
#undef EDGE

    const float ep = 1.0f + eps[l];
    float zl = fmaf(ep, bflo(gs), accA.x + accB.x);
    float zh = fmaf(ep, bfhi(gs), accA.y + accB.y);
    zq[(size_t)node * 64 + lane] = ((uint32)f2bf(zh) << 16) | (uint32)f2bf(zl);
}

// ---------------- MFMA MLP, operand-swapped, 1 wave / 16 rows per block ----------------
#define T_STRIDE 136   // shorts; 272B rows: 16B-aligned for b128 reads
__global__ __launch_bounds__(64) void mlp_mfma(
        const ushort16* __restrict__ zq,     // [N64][128] bf16
        const ushort16* __restrict__ Wb1t,   // [128 n][128 k] bf16
        const float* __restrict__ b1,
        const ushort16* __restrict__ Wb2t,
        const float* __restrict__ b2,
        ushort16* __restrict__ h_out, int N) {
    __shared__ ushort16 t_lds[16 * T_STRIDE];
    const int lane = threadIdx.x & 63;
    const int c = lane & 15, g = lane >> 4;
    const int wrow0 = blockIdx.x * 16;            // node-tile base

    // ---- GEMM1: t^T = W1^T @ z^T ----
    const ushort16* zrow = zq + (size_t)(wrow0 + c) * HDIM + g * 8;
    short8 bf[4];
#pragma unroll
    for (int kk = 0; kk < 4; ++kk)
        bf[kk] = *(const short8*)(zrow + kk * 32);

    f32x4 acc[8];
#pragma unroll
    for (int n = 0; n < 8; ++n) {
        float4 bb = *(const float4*)(b1 + n * 16 + g * 4);
        acc[n] = (f32x4){bb.x, bb.y, bb.z, bb.w};
    }
#pragma unroll
    for (int kk = 0; kk < 4; ++kk) {
#pragma unroll
        for (int n = 0; n < 8; ++n) {
            short8 af = *(const short8*)(Wb1t + (size_t)(n * 16 + c) * HDIM + kk * 32 + g * 8);
            acc[n] = __builtin_amdgcn_mfma_f32_16x16x32_bf16(af, bf[kk], acc[n], 0, 0, 0);
        }
    }
#pragma unroll
    for (int n = 0; n < 8; ++n) {
        ushort4 u;
        u.x = f2bf(fmaxf(acc[n][0], 0.f));
        u.y = f2bf(fmaxf(acc[n][1], 0.f));
        u.z = f2bf(fmaxf(acc[n][2], 0.f));
        u.w = f2bf(fmaxf(acc[n][3], 0.f));
        *(ushort4*)(&t_lds[c * T_STRIDE + n * 16 + g * 4]) = u;
    }
    __syncthreads();

    // ---- GEMM2: h^T = W2^T @ t^T ----
    short8 bf2[4];
#pragma unroll
    for (int kk = 0; kk < 4; ++kk)
        bf2[kk] = *(const short8*)(&t_lds[c * T_STRIDE + kk * 32 + g * 8]);

    f32x4 acc2[8];
#pragma unroll
    for (int n = 0; n < 8; ++n) {
        float4 bb = *(const float4*)(b2 + n * 16 + g * 4);
        acc2[n] = (f32x4){bb.x, bb.y, bb.z, bb.w};
    }
#pragma unroll
    for (int kk = 0; kk < 4; ++kk) {
#pragma unroll
        for (int n = 0; n < 8; ++n) {
            short8 af = *(const short8*)(Wb2t + (size_t)(n * 16 + c) * HDIM + kk * 32 + g * 8);
            acc2[n] = __builtin_amdgcn_mfma_f32_16x16x32_bf16(af, bf2[kk], acc2[n], 0, 0, 0);
        }
    }
    if (wrow0 + c < N) {
#pragma unroll
        for (int n = 0; n < 8; ++n) {
            ushort4 u;
            u.x = f2bf(fmaxf(acc2[n][0], 0.f));
            u.y = f2bf(fmaxf(acc2[n][1], 0.f));
            u.z = f2bf(fmaxf(acc2[n][2], 0.f));
            u.w = f2bf(fmaxf(acc2[n][3], 0.f));
            *(ushort4*)(h_out + (size_t)(wrow0 + c) * HDIM + n * 16 + g * 4) = u;
        }
    }
}

// ---------------- output projection: LDS-staged h rows ----------------
__global__ __launch_bounds__(256) void out_kernel(
        const uint32* __restrict__ hq, const float* __restrict__ Wout,
        const float* __restrict__ bout, float* __restrict__ out, int N) {
    __shared__ uint32 rows[16][64];
    const int tid = threadIdx.x;
    const int n0 = blockIdx.x * 16;
#pragma unroll
    for (int s = 0; s < 4; ++s) {
        int idx = tid + s * 256;           // 0..1023
        int r = idx >> 6, cc = idx & 63;
        int n = n0 + r;
        rows[r][cc] = (n < N) ? hq[(size_t)n * 64 + cc] : 0u;
    }
    __syncthreads();
    const int r = tid >> 4, pe = tid & 15;
    const int n = n0 + r;
    if (n >= N) return;
    float acc = bout[pe];
#pragma unroll 8
    for (int k2 = 0; k2 < 64; ++k2) {
        uint32 g = rows[r][k2];
        acc = fmaf(bflo(g), Wout[(2 * k2) * 16 + pe], acc);
        acc = fmaf(bfhi(g), Wout[(2 * k2 + 1) * 16 + pe], acc);
    }
    out[(size_t)n * 16 + pe] = acc;
}

extern "C" void kernel_launch(void* const* d_in, const int* in_sizes, int n_in,
                              void* d_out, int out_size, void* d_ws, size_t ws_size,
                              hipStream_t stream) {
    const int*   x_type     = (const int*)  d_in[0];
    const float* x_feat     = (const float*)d_in[1];
    const int*   edge_index = (const int*)  d_in[2];
    const float* edge_attr  = (const float*)d_in[3];
    const float* type_embed = (const float*)d_in[4];
    const float* featW      = (const float*)d_in[5];
    const float* featb      = (const float*)d_in[6];
    const float* edgeW      = (const float*)d_in[7];
    const float* edgeb      = (const float*)d_in[8];
    const float* W1         = (const float*)d_in[9];
    const float* b1         = (const float*)d_in[10];
    const float* W2         = (const float*)d_in[11];
    const float* b2         = (const float*)d_in[12];
    const float* eps        = (const float*)d_in[13];
    const float* Wout       = (const float*)d_in[14];
    const float* bout       = (const float*)d_in[15];

    const int N = in_sizes[0];
    const int E = in_sizes[2] / 2;
    const int L = in_sizes[13];
    const int N64 = (N + 63) & ~63;        // padded node buffers
    const int NB  = (N + NPB - 1) / NPB;   // 196 buckets
    const int M   = NB * NCH;              // histogram matrix size

    const int* srcIdx = edge_index;
    const int* dstIdx = edge_index + E;

    auto align256 = [](size_t x) { return (x + 255) & ~(size_t)255; };
    char* p = (char*)d_ws;
    ushort16* h_buf  = (ushort16*)p;           p += align256((size_t)N64 * HDIM * 2);
    ushort16* z_buf  = (ushort16*)p;           p += align256((size_t)N64 * HDIM * 2);
    int*   row_ptr   = (int*)p;                p += align256((size_t)(N + 1) * 4);
    int*   histM     = (int*)p;                p += align256((size_t)M * 4);
    int*   Fscan     = (int*)p;                p += align256((size_t)M * 4);
    int*   partials  = (int*)p;                p += align256(1024 * 4);
    int*   offsets   = (int*)p;                p += align256(1024 * 4);
    int*   done      = (int*)p;                p += align256(256);
    int4*  tmp       = (int4*)p;               p += align256((size_t)E * 16);
    int4*  adj       = (int4*)p;               p += align256((size_t)E * 16);
    ushort16* Wb1t   = (ushort16*)p;           p += align256((size_t)L * HDIM * HDIM * 2);
    ushort16* Wb2t   = (ushort16*)p;           p += align256((size_t)L * HDIM * HDIM * 2);
    (void)ws_size;

    const int wtotal = L * HDIM * HDIM;                 // 49152
    const int prepB  = (wtotal + 255) / 256;            // 192
    const int embedB = ((int)((size_t)N * HDIM) + 255) / 256;  // 25000

    // ---- fused preprocessing: hist || prep || embed ----
    pre_kernel<<<NCH + prepB + embedB, 256, 0, stream>>>(
        dstIdx, histM, E, NB,
        W1, W2, Wb1t, Wb2t, wtotal,
        x_type, x_feat, type_embed, featW, featb, h_buf, N,
        done, prepB);

    // ---- scan: partial sums + top scan in one dispatch, then per-block excl ----
    const int pblocks = (M + 1023) / 1024;              // 196
    partial_scan_kernel<<<pblocks, 1024, 0, stream>>>(histM, partials, offsets, done, M, pblocks);
    excl_out_kernel<<<pblocks, 1024, 0, stream>>>(histM, offsets, Fscan, M);
    chunk_scatter_kernel<<<NCH, 256, 0, stream>>>(srcIdx, dstIdx, edge_attr, Fscan, tmp, E, NB);
    bucket_sort_kernel<<<NB, 256, 0, stream>>>(tmp, Fscan, row_ptr, adj, E, NB, N);

    const int mlp_blocks = (N + 15) / 16;   // 3125 one-wave blocks
    for (int l = 0; l < L; ++l) {
        agg_kernel<<<(N + 1) / 2, 128, 0, stream>>>(
            (const uint32*)h_buf, row_ptr, adj, edgeW, edgeb, eps, l,
            (uint32*)z_buf, N);
        mlp_mfma<<<mlp_blocks, 64, 0, stream>>>(
            z_buf, Wb1t + (size_t)l * HDIM * HDIM, b1 + (size_t)l * HDIM,
            Wb2t + (size_t)l * HDIM * HDIM, b2 + (size_t)l * HDIM, h_buf, N);
    }

    out_kernel<<<(N + 15) / 16, 256, 0, stream>>>(
        (const uint32*)h_buf, Wout, bout, (float*)d_out, N);
}